// Round 14
// baseline (2180.713 us; speedup 1.0000x reference)
//
#include <hip/hip_runtime.h>

#define N_PTS  16384
#define B_SZ   8
#define NGROUP 1024
#define KNN_K  32
#define ATTR   7

// d_out layout (floats), reference return order:
// neighborhood (8,1024,32,7), center_idx (8,1024), centroids_attrs (8,1024,7), centroids_coors (8,1024,3)
#define OFF_NB     0
#define OFF_IDX    (B_SZ * NGROUP * KNN_K * ATTR)            // 1835008
#define OFF_CATTR  (OFF_IDX + B_SZ * NGROUP)                 // 1843200
#define OFF_CCOORD (OFF_CATTR + B_SZ * NGROUP * ATTR)        // 1900544

typedef float v2f __attribute__((ext_vector_type(2)));                 // packed-f32 math
typedef float f2u __attribute__((ext_vector_type(2), aligned(4)));     // 4B-aligned vec load

// ---------------------------------------------------------------------------
// DPP 64-lane reductions (VALU-only; no DS-pipe traffic).
// ---------------------------------------------------------------------------
template <int CTRL>
__device__ __forceinline__ float fmax_dpp_step(float x) {
    int d = __builtin_amdgcn_update_dpp(__float_as_int(x), __float_as_int(x),
                                        CTRL, 0xf, 0xf, false);
    return fmaxf(x, __int_as_float(d));
}
template <int CTRL>
__device__ __forceinline__ unsigned umin_dpp_step(unsigned x) {
    unsigned d = (unsigned)__builtin_amdgcn_update_dpp((int)x, (int)x,
                                                       CTRL, 0xf, 0xf, false);
    return x < d ? x : d;
}

__device__ __forceinline__ float wave_max_f32(float x) {
    x = fmax_dpp_step<0x111>(x);   // row_shr:1
    x = fmax_dpp_step<0x112>(x);   // row_shr:2
    x = fmax_dpp_step<0x114>(x);   // row_shr:4
    x = fmax_dpp_step<0x118>(x);   // row_shr:8
    x = fmax_dpp_step<0x142>(x);   // row_bcast15
    x = fmax_dpp_step<0x143>(x);   // row_bcast31 -> lane63 = full-wave max
    return __int_as_float(__builtin_amdgcn_readlane(__float_as_int(x), 63));
}
__device__ __forceinline__ unsigned wave_min_u32(unsigned x) {
    x = umin_dpp_step<0x111>(x);
    x = umin_dpp_step<0x112>(x);
    x = umin_dpp_step<0x114>(x);
    x = umin_dpp_step<0x118>(x);
    x = umin_dpp_step<0x142>(x);
    x = umin_dpp_step<0x143>(x);
    return (unsigned)__builtin_amdgcn_readlane((int)x, 63);
}

// ---------------------------------------------------------------------------
// Kernel 0: prep — x2[b][n] = sum_a xyz[b][n][a]^2 (sequential, no FMA) and
// SoA transpose xt[b][a][n] for coalesced KNN reads.
// ---------------------------------------------------------------------------
__global__ void prep_kernel(const float* __restrict__ xyz, float* __restrict__ x2,
                            float* __restrict__ xt) {
#pragma clang fp contract(off)
    int i = blockIdx.x * blockDim.x + threadIdx.x;
    if (i >= B_SZ * N_PTS) return;
    const int b = i >> 14;
    const int p = i & (N_PTS - 1);
    const float* q = xyz + (size_t)i * ATTR;
    f2u a01 = *(const f2u*)q;
    f2u a23 = *(const f2u*)(q + 2);
    f2u a45 = *(const f2u*)(q + 4);
    float a6 = q[6];
    float s = a01.x * a01.x;
    s = s + a01.y * a01.y;
    s = s + a23.x * a23.x;
    s = s + a23.y * a23.y;
    s = s + a45.x * a45.x;
    s = s + a45.y * a45.y;
    s = s + a6 * a6;
    x2[i] = s;
    float* T = xt + (size_t)b * ATTR * N_PTS + p;
    T[0 * N_PTS] = a01.x;
    T[1 * N_PTS] = a01.y;
    T[2 * N_PTS] = a23.x;
    T[3 * N_PTS] = a23.y;
    T[4 * N_PTS] = a45.x;
    T[5 * N_PTS] = a45.y;
    T[6 * N_PTS] = a6;
}

// ---------------------------------------------------------------------------
// Kernel 1: farthest point sampling. R14: 256 threads/block — the endpoint of
// the measured wave-count trend (16 waves: 1730us, 8 waves: 1552us; tail
// replication shrinks with wave count; scan issue/CU is wave-count-invariant
// with 32 independent pair-groups of ILP). 64 pts/thread as named v2f locals
// (~280 VGPR demand); amdgpu_waves_per_eu(1,1) gives RA a 512-VGPR budget
// (HW: no spill through 450, m08/m24); volatile coordinate loads keep the
// planes resident (R4-proven recipe). Triple-buffered LDS atomicMax combine
// (now only 4 serialized lanes), scalar winner fetch.
// Math: unfused, sequential, contract off. Per-thread ascending scan order,
// strict '>', wave umin tie-break, key (d-bits<<32 | 16384-idx) ->
// np.argmax first-max-wins exact — selections bit-identical to R4-R13.
// ---------------------------------------------------------------------------
#define FOR32(M) M(0) M(1) M(2) M(3) M(4) M(5) M(6) M(7) \
                 M(8) M(9) M(10) M(11) M(12) M(13) M(14) M(15) \
                 M(16) M(17) M(18) M(19) M(20) M(21) M(22) M(23) \
                 M(24) M(25) M(26) M(27) M(28) M(29) M(30) M(31)

#define PT_DECL(J) v2f px##J, py##J, pz##J, pd##J;

#define PT_LOAD(J) { \
    const int p0 = t + ((2 * J) << 8); \
    const float* q0 = X + (size_t)p0 * ATTR; \
    const float* q1 = q0 + (size_t)256 * ATTR; \
    f2u u0 = *(const volatile f2u*)q0; float z0 = ((const volatile float*)q0)[2]; \
    f2u u1 = *(const volatile f2u*)q1; float z1 = ((const volatile float*)q1)[2]; \
    px##J = (v2f){u0.x, u1.x}; \
    py##J = (v2f){u0.y, u1.y}; \
    pz##J = (v2f){z0, z1}; \
    pd##J = (v2f){1e10f, 1e10f}; }

#define PT_STEP(J) { \
    v2f dx = px##J - cx2; \
    v2f dy = py##J - cy2; \
    v2f dz = pz##J - cz2; \
    v2f a  = dx * dx; \
    a = a + dy * dy; \
    a = a + dz * dz; \
    v2f nd; \
    nd.x = fminf(pd##J.x, a.x); \
    nd.y = fminf(pd##J.y, a.y); \
    pd##J = nd; \
    if (nd.x > best) { best = nd.x; bidx = t + ((2 * J) << 8); } \
    if (nd.y > best) { best = nd.y; bidx = t + ((2 * J + 1) << 8); } }

__global__ __launch_bounds__(256)
__attribute__((amdgpu_waves_per_eu(1, 1)))
void fps_kernel(const float* __restrict__ xyz, float* __restrict__ out) {
#pragma clang fp contract(off)
    const int b = blockIdx.x;
    const int t = threadIdx.x;
    const int lane = t & 63;
    const float* X = xyz + (size_t)b * N_PTS * ATTR;

    FOR32(PT_DECL)
    FOR32(PT_LOAD)

    __shared__ unsigned long long slot[3];
    __shared__ int sel[NGROUP];
    if (t == 0) { slot[0] = 0ull; sel[0] = 0; }
    float cx = X[0], cy = X[1], cz = X[2];     // farthest=0 initial centroid
    __syncthreads();

    for (int s = 0; s < NGROUP - 1; ++s) {
        const v2f cx2 = {cx, cx}, cy2 = {cy, cy}, cz2 = {cz, cz};
        float best = -1.0f;
        int   bidx = 0;
        // strict '>' + per-thread ascending scan order == np.argmax semantics.
        FOR32(PT_STEP)
        // wave-level: max distance, then smallest point index among exact ties.
        const float wm = wave_max_f32(best);
        const unsigned cand = (best == wm) ? (unsigned)bidx : 0xFFFFFFFFu;
        const unsigned widx = wave_min_u32(cand);
        if (lane == 0) {
            // d >= 0 so float bits are order-preserving as u32.
            const unsigned long long key =
                ((unsigned long long)__float_as_uint(wm) << 32) |
                (unsigned)(N_PTS - widx);
            atomicMax(&slot[s % 3], key);
        }
        // reset the NEXT step's slot now: reads of this slot happened at step
        // s-2 (before barrier s-1); next step's atomics happen after barrier s.
        if (t == 0) slot[(s + 1) % 3] = 0ull;
        __syncthreads();
        const unsigned long long bk = slot[s % 3];
        const int win = N_PTS - (int)(unsigned)bk;
        const int sbidx = __builtin_amdgcn_readfirstlane(win);
        if (t == 0) sel[s + 1] = sbidx;
        // uniform (SGPR) address -> scalar load of winner coords, L2-hit.
        const float* q = X + (size_t)sbidx * ATTR;
        cx = q[0]; cy = q[1]; cz = q[2];
    }
    __syncthreads();

    // outputs: center_idx, centroids_attrs, centroids_coors (1024 groups, 256 threads)
    for (int g = t; g < NGROUP; g += 256) {
        const int idx = sel[g];
        const float* q = X + (size_t)idx * ATTR;
        float a0 = q[0], a1 = q[1], a2 = q[2], a3 = q[3], a4 = q[4], a5 = q[5], a6 = q[6];
        out[OFF_IDX + b * NGROUP + g] = (float)idx;
        float* ca = out + OFF_CATTR + (size_t)(b * NGROUP + g) * ATTR;
        ca[0] = a0; ca[1] = a1; ca[2] = a2; ca[3] = a3; ca[4] = a4; ca[5] = a5; ca[6] = a6;
        float* cc = out + OFF_CCOORD + (size_t)(b * NGROUP + g) * 3;
        cc[0] = a0; cc[1] = a1; cc[2] = a2;
    }
}

// ---------------------------------------------------------------------------
// distributed top-32 insert (sorted list lives one-slot-per-lane, lanes 0..31)
// ---------------------------------------------------------------------------
__device__ __forceinline__ void topk_insert(float d2, int p, int lane,
                                            float& ld, int& li, float& kd, int& ki) {
    const bool cand = (d2 < kd) || (d2 == kd && p < ki);
    unsigned long long mask = __ballot(cand);
    while (mask) {
        const int l = __ffsll(mask) - 1;
        mask &= mask - 1;
        const float dc = __shfl(d2, l);
        const int   pc = __shfl(p, l);
        if ((dc < kd) || (dc == kd && pc < ki)) {
            const bool before = (ld < dc) || (ld == dc && li < pc);
            const int pos = (int)__popcll(__ballot(before));
            const float sd = __shfl_up(ld, 1);
            const int   si = __shfl_up(li, 1);
            if (lane == pos)      { ld = dc; li = pc; }
            else if (lane > pos)  { ld = sd; li = si; }
            if (lane >= KNN_K)    { ld = __builtin_inff(); li = 0x7fffffff; }
            kd = __shfl(ld, KNN_K - 1);
            ki = __shfl(li, KNN_K - 1);
        }
    }
}

// ---------------------------------------------------------------------------
// Kernel 2: 32-NN in 7-D + gather/recenter — UNCHANGED from R13 (best
// measured: rest ~318 us). One wave per group, 4 groups per block, global
// SoA reads. knn is L2-supplied on a saturated grid; R11's wave-split and
// R12's LDS staging both regressed. d2 = (c2+x2)-2*dot, sums sequential,
// unfused, contract off.
// ---------------------------------------------------------------------------
__global__ __launch_bounds__(256) void knn_kernel(const float* __restrict__ xyz,
                                                  const float* __restrict__ x2,
                                                  const float* __restrict__ xt,
                                                  float* __restrict__ out) {
#pragma clang fp contract(off)
    const int lane = threadIdx.x & 63;
    const int gg = blockIdx.x * 4 + (threadIdx.x >> 6);   // global group 0..8191
    const int b  = gg >> 10;
    const float* X = xyz + (size_t)b * N_PTS * ATTR;

    const float* C = out + OFF_CATTR + (size_t)gg * ATTR;
    const float c0 = C[0], c1 = C[1], c2a = C[2], c3 = C[3], c4 = C[4], c5 = C[5], c6 = C[6];
    float csq = c0 * c0;
    csq = csq + c1 * c1;
    csq = csq + c2a * c2a;
    csq = csq + c3 * c3;
    csq = csq + c4 * c4;
    csq = csq + c5 * c5;
    csq = csq + c6 * c6;

    float ld = __builtin_inff();
    int   li = 0x7fffffff;
    float kd = __builtin_inff();
    int   ki = 0x7fffffff;

    if (xt != nullptr) {
        const float* T0 = xt + (size_t)b * ATTR * N_PTS;
        const float* T1 = T0 + N_PTS;
        const float* T2 = T1 + N_PTS;
        const float* T3 = T2 + N_PTS;
        const float* T4 = T3 + N_PTS;
        const float* T5 = T4 + N_PTS;
        const float* T6 = T5 + N_PTS;
        const float* XB = x2 + (size_t)b * N_PTS;
        for (int p0 = 0; p0 < N_PTS; p0 += 64) {
            const int p = p0 + lane;
            const float q0 = T0[p], q1 = T1[p], q2 = T2[p], q3 = T3[p];
            const float q4 = T4[p], q5 = T5[p], q6 = T6[p];
            float dot = c0 * q0;
            dot = dot + c1 * q1;
            dot = dot + c2a * q2;
            dot = dot + c3 * q3;
            dot = dot + c4 * q4;
            dot = dot + c5 * q5;
            dot = dot + c6 * q6;
            const float xx = XB[p];
            const float d2 = (csq + xx) - 2.0f * dot;
            topk_insert(d2, p, lane, ld, li, kd, ki);
        }
    } else {
        for (int p0 = 0; p0 < N_PTS; p0 += 64) {
            const int p = p0 + lane;
            const float* q = X + (size_t)p * ATTR;
            float dot = c0 * q[0];
            dot = dot + c1 * q[1];
            dot = dot + c2a * q[2];
            dot = dot + c3 * q[3];
            dot = dot + c4 * q[4];
            dot = dot + c5 * q[5];
            dot = dot + c6 * q[6];
            float xx = q[0] * q[0];
            xx = xx + q[1] * q[1];
            xx = xx + q[2] * q[2];
            xx = xx + q[3] * q[3];
            xx = xx + q[4] * q[4];
            xx = xx + q[5] * q[5];
            xx = xx + q[6] * q[6];
            const float d2 = (csq + xx) - 2.0f * dot;
            topk_insert(d2, p, lane, ld, li, kd, ki);
        }
    }

    // neighborhood output: lane j writes rank-j neighbor (ascending (d2,idx))
    if (lane < KNN_K) {
        const float* q = X + (size_t)li * ATTR;
        float* o = out + OFF_NB + ((size_t)gg * KNN_K + lane) * ATTR;
        o[0] = q[0] - c0;
        o[1] = q[1] - c1;
        o[2] = q[2] - c2a;
        o[3] = q[3];
        o[4] = q[4];
        o[5] = q[5];
        o[6] = q[6];
    }
}

extern "C" void kernel_launch(void* const* d_in, const int* in_sizes, int n_in,
                              void* d_out, int out_size, void* d_ws, size_t ws_size,
                              hipStream_t stream) {
    const float* xyz = (const float*)d_in[0];
    float* out = (float*)d_out;

    const size_t need = (size_t)(B_SZ * N_PTS) * (1 + ATTR) * sizeof(float);  // 4 MiB
    const bool use_ws = ws_size >= need;
    float* x2 = use_ws ? (float*)d_ws : nullptr;
    float* xt = use_ws ? ((float*)d_ws + B_SZ * N_PTS) : nullptr;

    if (use_ws) {
        prep_kernel<<<(B_SZ * N_PTS + 255) / 256, 256, 0, stream>>>(xyz, x2, xt);
    }
    fps_kernel<<<B_SZ, 256, 0, stream>>>(xyz, out);
    knn_kernel<<<(B_SZ * NGROUP) / 4, 256, 0, stream>>>(xyz, x2, xt, out);
}

// Round 15
// 1854.859 us; speedup vs baseline: 1.1757x; 1.1757x over previous
//
#include <hip/hip_runtime.h>

#define N_PTS  16384
#define B_SZ   8
#define NGROUP 1024
#define KNN_K  32
#define ATTR   7

// d_out layout (floats), reference return order:
// neighborhood (8,1024,32,7), center_idx (8,1024), centroids_attrs (8,1024,7), centroids_coors (8,1024,3)
#define OFF_NB     0
#define OFF_IDX    (B_SZ * NGROUP * KNN_K * ATTR)            // 1835008
#define OFF_CATTR  (OFF_IDX + B_SZ * NGROUP)                 // 1843200
#define OFF_CCOORD (OFF_CATTR + B_SZ * NGROUP * ATTR)        // 1900544

typedef float v2f __attribute__((ext_vector_type(2)));                 // packed-f32 math
typedef float f2u __attribute__((ext_vector_type(2), aligned(4)));     // 4B-aligned vec load

// ---------------------------------------------------------------------------
// DPP 64-lane reductions (VALU-only; no DS-pipe traffic).
// ---------------------------------------------------------------------------
template <int CTRL>
__device__ __forceinline__ float fmax_dpp_step(float x) {
    int d = __builtin_amdgcn_update_dpp(__float_as_int(x), __float_as_int(x),
                                        CTRL, 0xf, 0xf, false);
    return fmaxf(x, __int_as_float(d));
}
template <int CTRL>
__device__ __forceinline__ unsigned umin_dpp_step(unsigned x) {
    unsigned d = (unsigned)__builtin_amdgcn_update_dpp((int)x, (int)x,
                                                       CTRL, 0xf, 0xf, false);
    return x < d ? x : d;
}

__device__ __forceinline__ float wave_max_f32(float x) {
    x = fmax_dpp_step<0x111>(x);   // row_shr:1
    x = fmax_dpp_step<0x112>(x);   // row_shr:2
    x = fmax_dpp_step<0x114>(x);   // row_shr:4
    x = fmax_dpp_step<0x118>(x);   // row_shr:8
    x = fmax_dpp_step<0x142>(x);   // row_bcast15
    x = fmax_dpp_step<0x143>(x);   // row_bcast31 -> lane63 = full-wave max
    return __int_as_float(__builtin_amdgcn_readlane(__float_as_int(x), 63));
}
__device__ __forceinline__ unsigned wave_min_u32(unsigned x) {
    x = umin_dpp_step<0x111>(x);
    x = umin_dpp_step<0x112>(x);
    x = umin_dpp_step<0x114>(x);
    x = umin_dpp_step<0x118>(x);
    x = umin_dpp_step<0x142>(x);
    x = umin_dpp_step<0x143>(x);
    return (unsigned)__builtin_amdgcn_readlane((int)x, 63);
}

// ---------------------------------------------------------------------------
// Kernel 0: prep — x2[b][n] = sum_a xyz[b][n][a]^2 (sequential, no FMA) and
// SoA transpose xt[b][a][n] for coalesced KNN reads.
// ---------------------------------------------------------------------------
__global__ void prep_kernel(const float* __restrict__ xyz, float* __restrict__ x2,
                            float* __restrict__ xt) {
#pragma clang fp contract(off)
    int i = blockIdx.x * blockDim.x + threadIdx.x;
    if (i >= B_SZ * N_PTS) return;
    const int b = i >> 14;
    const int p = i & (N_PTS - 1);
    const float* q = xyz + (size_t)i * ATTR;
    f2u a01 = *(const f2u*)q;
    f2u a23 = *(const f2u*)(q + 2);
    f2u a45 = *(const f2u*)(q + 4);
    float a6 = q[6];
    float s = a01.x * a01.x;
    s = s + a01.y * a01.y;
    s = s + a23.x * a23.x;
    s = s + a23.y * a23.y;
    s = s + a45.x * a45.x;
    s = s + a45.y * a45.y;
    s = s + a6 * a6;
    x2[i] = s;
    float* T = xt + (size_t)b * ATTR * N_PTS + p;
    T[0 * N_PTS] = a01.x;
    T[1 * N_PTS] = a01.y;
    T[2 * N_PTS] = a23.x;
    T[3 * N_PTS] = a23.y;
    T[4 * N_PTS] = a45.x;
    T[5 * N_PTS] = a45.y;
    T[6 * N_PTS] = a6;
}

// ---------------------------------------------------------------------------
// Kernel 1: farthest point sampling — the converged best (1550-1560 us,
// reproduced rounds 11/12/13). 512 threads/block (8 waves = the measured
// minimum of the wave-count curve: 16w=1730, 8w=1552, 4w=1852), 32
// pts/thread as named v2f locals with volatile coordinate loads,
// waves_per_eu(2,2), triple-buffered LDS atomicMax combine, scalar winner
// fetch. VALU-issue-bound + serial tail on the 8 active CUs; R1-R14 tested
// storage (reg/LDS/scratch), pipelining, tail restructure, wave splits —
// all null or negative vs this configuration.
// Math: unfused, sequential, contract off. np.argmax first-max-wins exact.
// ---------------------------------------------------------------------------
#define FOR16(M) M(0) M(1) M(2) M(3) M(4) M(5) M(6) M(7) \
                 M(8) M(9) M(10) M(11) M(12) M(13) M(14) M(15)

#define PT_DECL(J) v2f px##J, py##J, pz##J, pd##J;

#define PT_LOAD(J) { \
    const int p0 = t + ((2 * J) << 9); \
    const float* q0 = X + (size_t)p0 * ATTR; \
    const float* q1 = q0 + (size_t)512 * ATTR; \
    f2u u0 = *(const volatile f2u*)q0; float z0 = ((const volatile float*)q0)[2]; \
    f2u u1 = *(const volatile f2u*)q1; float z1 = ((const volatile float*)q1)[2]; \
    px##J = (v2f){u0.x, u1.x}; \
    py##J = (v2f){u0.y, u1.y}; \
    pz##J = (v2f){z0, z1}; \
    pd##J = (v2f){1e10f, 1e10f}; }

#define PT_STEP(J) { \
    v2f dx = px##J - cx2; \
    v2f dy = py##J - cy2; \
    v2f dz = pz##J - cz2; \
    v2f a  = dx * dx; \
    a = a + dy * dy; \
    a = a + dz * dz; \
    v2f nd; \
    nd.x = fminf(pd##J.x, a.x); \
    nd.y = fminf(pd##J.y, a.y); \
    pd##J = nd; \
    if (nd.x > best) { best = nd.x; bidx = t + ((2 * J) << 9); } \
    if (nd.y > best) { best = nd.y; bidx = t + ((2 * J + 1) << 9); } }

__global__ __launch_bounds__(512)
__attribute__((amdgpu_waves_per_eu(2, 2)))
void fps_kernel(const float* __restrict__ xyz, float* __restrict__ out) {
#pragma clang fp contract(off)
    const int b = blockIdx.x;
    const int t = threadIdx.x;
    const int lane = t & 63;
    const float* X = xyz + (size_t)b * N_PTS * ATTR;

    FOR16(PT_DECL)
    FOR16(PT_LOAD)

    __shared__ unsigned long long slot[3];
    __shared__ int sel[NGROUP];
    if (t == 0) { slot[0] = 0ull; sel[0] = 0; }
    float cx = X[0], cy = X[1], cz = X[2];     // farthest=0 initial centroid
    __syncthreads();

    for (int s = 0; s < NGROUP - 1; ++s) {
        const v2f cx2 = {cx, cx}, cy2 = {cy, cy}, cz2 = {cz, cz};
        float best = -1.0f;
        int   bidx = 0;
        // strict '>' + per-thread ascending scan order == np.argmax semantics.
        FOR16(PT_STEP)
        // wave-level: max distance, then smallest point index among exact ties.
        const float wm = wave_max_f32(best);
        const unsigned cand = (best == wm) ? (unsigned)bidx : 0xFFFFFFFFu;
        const unsigned widx = wave_min_u32(cand);
        if (lane == 0) {
            // d >= 0 so float bits are order-preserving as u32.
            const unsigned long long key =
                ((unsigned long long)__float_as_uint(wm) << 32) |
                (unsigned)(N_PTS - widx);
            atomicMax(&slot[s % 3], key);
        }
        // reset the NEXT step's slot now: reads of this slot happened at step
        // s-2 (before barrier s-1); next step's atomics happen after barrier s.
        if (t == 0) slot[(s + 1) % 3] = 0ull;
        __syncthreads();
        const unsigned long long bk = slot[s % 3];
        const int win = N_PTS - (int)(unsigned)bk;
        const int sbidx = __builtin_amdgcn_readfirstlane(win);
        if (t == 0) sel[s + 1] = sbidx;
        // uniform (SGPR) address -> scalar load of winner coords, L2-hit.
        const float* q = X + (size_t)sbidx * ATTR;
        cx = q[0]; cy = q[1]; cz = q[2];
    }
    __syncthreads();

    // outputs: center_idx, centroids_attrs, centroids_coors (1024 groups, 512 threads)
    for (int g = t; g < NGROUP; g += 512) {
        const int idx = sel[g];
        const float* q = X + (size_t)idx * ATTR;
        float a0 = q[0], a1 = q[1], a2 = q[2], a3 = q[3], a4 = q[4], a5 = q[5], a6 = q[6];
        out[OFF_IDX + b * NGROUP + g] = (float)idx;
        float* ca = out + OFF_CATTR + (size_t)(b * NGROUP + g) * ATTR;
        ca[0] = a0; ca[1] = a1; ca[2] = a2; ca[3] = a3; ca[4] = a4; ca[5] = a5; ca[6] = a6;
        float* cc = out + OFF_CCOORD + (size_t)(b * NGROUP + g) * 3;
        cc[0] = a0; cc[1] = a1; cc[2] = a2;
    }
}

// ---------------------------------------------------------------------------
// distributed top-32 insert (sorted list lives one-slot-per-lane, lanes 0..31)
// ---------------------------------------------------------------------------
__device__ __forceinline__ void topk_insert(float d2, int p, int lane,
                                            float& ld, int& li, float& kd, int& ki) {
    const bool cand = (d2 < kd) || (d2 == kd && p < ki);
    unsigned long long mask = __ballot(cand);
    while (mask) {
        const int l = __ffsll(mask) - 1;
        mask &= mask - 1;
        const float dc = __shfl(d2, l);
        const int   pc = __shfl(p, l);
        if ((dc < kd) || (dc == kd && pc < ki)) {
            const bool before = (ld < dc) || (ld == dc && li < pc);
            const int pos = (int)__popcll(__ballot(before));
            const float sd = __shfl_up(ld, 1);
            const int   si = __shfl_up(li, 1);
            if (lane == pos)      { ld = dc; li = pc; }
            else if (lane > pos)  { ld = sd; li = si; }
            if (lane >= KNN_K)    { ld = __builtin_inff(); li = 0x7fffffff; }
            kd = __shfl(ld, KNN_K - 1);
            ki = __shfl(li, KNN_K - 1);
        }
    }
}

// ---------------------------------------------------------------------------
// Kernel 2: 32-NN in 7-D + gather/recenter — the converged best (rest ~318
// us). One wave per group, 4 groups per block, global SoA reads (7+1
// coalesced dwords per 64-point batch). knn is L2-supplied on a saturated
// grid; wave-splits (R11) and LDS staging (R12) both regressed.
// d2 = (c2+x2)-2*dot, sums sequential, unfused, contract off.
// ---------------------------------------------------------------------------
__global__ __launch_bounds__(256) void knn_kernel(const float* __restrict__ xyz,
                                                  const float* __restrict__ x2,
                                                  const float* __restrict__ xt,
                                                  float* __restrict__ out) {
#pragma clang fp contract(off)
    const int lane = threadIdx.x & 63;
    const int gg = blockIdx.x * 4 + (threadIdx.x >> 6);   // global group 0..8191
    const int b  = gg >> 10;
    const float* X = xyz + (size_t)b * N_PTS * ATTR;

    const float* C = out + OFF_CATTR + (size_t)gg * ATTR;
    const float c0 = C[0], c1 = C[1], c2a = C[2], c3 = C[3], c4 = C[4], c5 = C[5], c6 = C[6];
    float csq = c0 * c0;
    csq = csq + c1 * c1;
    csq = csq + c2a * c2a;
    csq = csq + c3 * c3;
    csq = csq + c4 * c4;
    csq = csq + c5 * c5;
    csq = csq + c6 * c6;

    float ld = __builtin_inff();
    int   li = 0x7fffffff;
    float kd = __builtin_inff();
    int   ki = 0x7fffffff;

    if (xt != nullptr) {
        const float* T0 = xt + (size_t)b * ATTR * N_PTS;
        const float* T1 = T0 + N_PTS;
        const float* T2 = T1 + N_PTS;
        const float* T3 = T2 + N_PTS;
        const float* T4 = T3 + N_PTS;
        const float* T5 = T4 + N_PTS;
        const float* T6 = T5 + N_PTS;
        const float* XB = x2 + (size_t)b * N_PTS;
        for (int p0 = 0; p0 < N_PTS; p0 += 64) {
            const int p = p0 + lane;
            const float q0 = T0[p], q1 = T1[p], q2 = T2[p], q3 = T3[p];
            const float q4 = T4[p], q5 = T5[p], q6 = T6[p];
            float dot = c0 * q0;
            dot = dot + c1 * q1;
            dot = dot + c2a * q2;
            dot = dot + c3 * q3;
            dot = dot + c4 * q4;
            dot = dot + c5 * q5;
            dot = dot + c6 * q6;
            const float xx = XB[p];
            const float d2 = (csq + xx) - 2.0f * dot;
            topk_insert(d2, p, lane, ld, li, kd, ki);
        }
    } else {
        for (int p0 = 0; p0 < N_PTS; p0 += 64) {
            const int p = p0 + lane;
            const float* q = X + (size_t)p * ATTR;
            float dot = c0 * q[0];
            dot = dot + c1 * q[1];
            dot = dot + c2a * q[2];
            dot = dot + c3 * q[3];
            dot = dot + c4 * q[4];
            dot = dot + c5 * q[5];
            dot = dot + c6 * q[6];
            float xx = q[0] * q[0];
            xx = xx + q[1] * q[1];
            xx = xx + q[2] * q[2];
            xx = xx + q[3] * q[3];
            xx = xx + q[4] * q[4];
            xx = xx + q[5] * q[5];
            xx = xx + q[6] * q[6];
            const float d2 = (csq + xx) - 2.0f * dot;
            topk_insert(d2, p, lane, ld, li, kd, ki);
        }
    }

    // neighborhood output: lane j writes rank-j neighbor (ascending (d2,idx))
    if (lane < KNN_K) {
        const float* q = X + (size_t)li * ATTR;
        float* o = out + OFF_NB + ((size_t)gg * KNN_K + lane) * ATTR;
        o[0] = q[0] - c0;
        o[1] = q[1] - c1;
        o[2] = q[2] - c2a;
        o[3] = q[3];
        o[4] = q[4];
        o[5] = q[5];
        o[6] = q[6];
    }
}

extern "C" void kernel_launch(void* const* d_in, const int* in_sizes, int n_in,
                              void* d_out, int out_size, void* d_ws, size_t ws_size,
                              hipStream_t stream) {
    const float* xyz = (const float*)d_in[0];
    float* out = (float*)d_out;

    const size_t need = (size_t)(B_SZ * N_PTS) * (1 + ATTR) * sizeof(float);  // 4 MiB
    const bool use_ws = ws_size >= need;
    float* x2 = use_ws ? (float*)d_ws : nullptr;
    float* xt = use_ws ? ((float*)d_ws + B_SZ * N_PTS) : nullptr;

    if (use_ws) {
        prep_kernel<<<(B_SZ * N_PTS + 255) / 256, 256, 0, stream>>>(xyz, x2, xt);
    }
    fps_kernel<<<B_SZ, 512, 0, stream>>>(xyz, out);
    knn_kernel<<<(B_SZ * NGROUP) / 4, 256, 0, stream>>>(xyz, x2, xt, out);
}